// Round 1
// baseline (40.782 us; speedup 1.0000x reference)
//
#include <hip/hip_runtime.h>

// Phase 1: out[b, item, f] = emb_weight[item, f] for all b.
// One thread per float4 of emb_weight; each writes B batch slices.
__global__ void fill_bcast(const float4* __restrict__ emb,
                           float4* __restrict__ out,
                           int n4 /* ITEMS*FEAT/4 */, int B) {
    int idx = blockIdx.x * blockDim.x + threadIdx.x;
    if (idx >= n4) return;
    float4 v = emb[idx];
    for (int b = 0; b < B; ++b) {
        out[(size_t)b * (size_t)n4 + (size_t)idx] = v;
    }
}

// Phase 2: for each flat node i (graph b), item = nodes[i]:
//   out[b, item, :] = (1 - alpha[item]) * emb[item, :] + alpha[item] * nodes_output[i, :]
// One thread per float4 of a row (FEAT/4 threads per node).
__global__ void scatter_upd(const float4* __restrict__ nodes_out,
                            const float4* __restrict__ emb,
                            const float* __restrict__ alpha,
                            const int* __restrict__ nodes,
                            const int* __restrict__ ptr,
                            float4* __restrict__ out,
                            int n_nodes, int B, int feat4, size_t items_feat4) {
    int gid = blockIdx.x * blockDim.x + threadIdx.x;
    int i = gid / feat4;
    int f = gid - i * feat4;
    if (i >= n_nodes) return;

    int item = nodes[i];
    // batch id: ptr[b] <= i < ptr[b+1]  (B is tiny; ptr is L1/scalar-cached)
    int b = 0;
    while (b + 1 < B && i >= ptr[b + 1]) ++b;

    float a = alpha[item];
    float4 e = emb[(size_t)item * (size_t)feat4 + (size_t)f];
    float4 x = nodes_out[(size_t)i * (size_t)feat4 + (size_t)f];
    float4 r;
    r.x = (1.0f - a) * e.x + a * x.x;
    r.y = (1.0f - a) * e.y + a * x.y;
    r.z = (1.0f - a) * e.z + a * x.z;
    r.w = (1.0f - a) * e.w + a * x.w;
    out[(size_t)b * items_feat4 + (size_t)item * (size_t)feat4 + (size_t)f] = r;
}

extern "C" void kernel_launch(void* const* d_in, const int* in_sizes, int n_in,
                              void* d_out, int out_size, void* d_ws, size_t ws_size,
                              hipStream_t stream) {
    const float* nodes_output = (const float*)d_in[0];   // [n_nodes, FEAT]
    const float* emb_weight   = (const float*)d_in[1];   // [ITEMS, FEAT]
    const float* alpha        = (const float*)d_in[2];   // [ITEMS, 1]
    const int*   nodes        = (const int*)d_in[3];     // [n_nodes]
    const int*   ptr          = (const int*)d_in[4];     // [B+1]

    const int n_nodes = in_sizes[3];
    const int items   = in_sizes[2];
    const int feat    = in_sizes[0] / n_nodes;   // 64
    const int B       = in_sizes[4] - 1;         // 8
    const int feat4   = feat / 4;                // 16
    const int n4      = items * feat4;           // ITEMS*FEAT/4 = 1.6M
    const size_t items_feat4 = (size_t)items * (size_t)feat4;

    float* out = (float*)d_out;

    // Phase 1: broadcast emb_weight into every batch slice.
    {
        int threads = 256;
        int blocks = (n4 + threads - 1) / threads;
        fill_bcast<<<blocks, threads, 0, stream>>>(
            (const float4*)emb_weight, (float4*)out, n4, B);
    }
    // Phase 2: scatter gated updates (runs after fill; same stream).
    {
        int total = n_nodes * feat4;             // 65536
        int threads = 256;
        int blocks = (total + threads - 1) / threads;
        scatter_upd<<<blocks, threads, 0, stream>>>(
            (const float4*)nodes_output, (const float4*)emb_weight, alpha,
            nodes, ptr, (float4*)out,
            n_nodes, B, feat4, items_feat4);
    }
}